// Round 2
// baseline (1617.352 us; speedup 1.0000x reference)
//
#include <hip/hip_runtime.h>

#define E_N 100000
#define NV_N 50000
#define NG_N 2000
#define KW 1088   // WT row stride: 1024 weights + bias row @1024 + pad

typedef short s8v __attribute__((ext_vector_type(8)));
typedef unsigned short u16x8 __attribute__((ext_vector_type(8)));
typedef float f32x4 __attribute__((ext_vector_type(4)));

__device__ __forceinline__ float bf2f(unsigned short u) {
  return __uint_as_float(((unsigned int)u) << 16);
}
__device__ __forceinline__ unsigned short f2bf(float f) {
  unsigned int u = __float_as_uint(f);
  u = u + 0x7fffu + ((u >> 16) & 1u);   // RNE
  return (unsigned short)(u >> 16);
}

__device__ __forceinline__ void gload_lds16(const void* g, void* l) {
  __builtin_amdgcn_global_load_lds((const __attribute__((address_space(1))) void*)g,
                                   (__attribute__((address_space(3))) void*)l, 16, 0, 0);
}

// ---------------- precompute kernels ----------------

// tabs: [4][256][1024] bf16. tb0: W1a rows0-7 + b1a; tb1: rows8-15; tb2/tb3: W2a.
__global__ void k_tables(const float* __restrict__ W1a, const float* __restrict__ b1a,
                         const float* __restrict__ W2a, const float* __restrict__ b2a,
                         unsigned short* __restrict__ tabs) {
  int tid = blockIdx.x * 256 + threadIdx.x;
  int tb = tid >> 18, v = (tid >> 10) & 255, k = tid & 1023;
  const float* W = (tb < 2) ? W1a : W2a;
  int rbase = (tb & 1) ? 8 : 0;
  float s = 0.f;
  if ((tb & 1) == 0) s = (tb < 2) ? b1a[k] : b2a[k];
  #pragma unroll
  for (int j = 0; j < 8; ++j)
    if ((v >> (7 - j)) & 1) s += W[(rbase + j) * 1024 + k];
  tabs[tid] = f2bf(s);
}

// dst[n*KW + k] = bf16(src[k*N + n]) ; K=1024, N mult of 32
__global__ void k_transpose(const float* __restrict__ src, unsigned short* __restrict__ dst,
                            int K, int N) {
  __shared__ float tile[32][33];
  int ntx = N >> 5;
  int tk = blockIdx.x / ntx, tn = blockIdx.x - tk * ntx;
  int k0 = tk * 32, n0 = tn * 32;
  int lx = threadIdx.x & 31, ly = threadIdx.x >> 5;
  #pragma unroll
  for (int yy = ly; yy < 32; yy += 8)
    tile[yy][lx] = src[(k0 + yy) * N + (n0 + lx)];
  __syncthreads();
  #pragma unroll
  for (int yy = ly; yy < 32; yy += 8)
    dst[(size_t)(n0 + yy) * KW + (k0 + lx)] = f2bf(tile[lx][yy]);
}

// fill WT[n][1024] = bvec[n], WT[n][1025..1087] = 0
__global__ void k_biasrow(const float* __restrict__ b, unsigned short* __restrict__ dst, int N) {
  int tid = blockIdx.x * 256 + threadIdx.x;
  if (tid >= N * 64) return;
  int n = tid >> 6, j = tid & 63;
  dst[(size_t)n * KW + 1024 + j] = (j == 0) ? f2bf(b[n]) : (unsigned short)0;
}

__global__ void k_count(const int* __restrict__ ei, int* __restrict__ cnt) {
  int e = blockIdx.x * 256 + threadIdx.x;
  if (e < E_N) atomicAdd(&cnt[ei[E_N + e]], 1);
}

// ---------------- fused edge NNConv kernel ----------------
// 512 thr (8 waves, 2wr x 4wc), 128 edges/block. theta GEMM via MFMA with
// counted-vmcnt B pipeline; A (hidden) register-resident per K-chunk of 128;
// per-lane msg ownership (o = wc*16+ll family) -> direct global atomics.
template<int NCOLS, int FOUT>
__global__ void __launch_bounds__(512)
k_edge(const float* __restrict__ xsrc, const int* __restrict__ ei,
       const int* __restrict__ eap,
       const unsigned short* __restrict__ tab0,
       const unsigned short* __restrict__ tab1,
       const unsigned short* __restrict__ WT,     // [NCOLS][KW] bf16
       float* __restrict__ agg)                   // [NV][FOUT] fp32, pre-zeroed
{
  constexpr int NC = NCOLS / 256;                 // 256-col slices
  constexpr int S8 = 8 * NC * 4;                  // stages in 8 full chunks
  constexpr int ST = S8 + NC;                     // + mini (bias) chunk stages

  __shared__ unsigned short sHid[128 * 128];      // 32KB, swizzled kb^(m&15)
  __shared__ unsigned short sB[3][256 * 32];      // 48KB, 3-deep stage ring
  __shared__ float sXf[128 * 32];                 // 16KB fp32 x rows
  __shared__ int sSrc[128], sDst[128];
  __shared__ unsigned char sb0[128], sb1[128];

  const int t = threadIdx.x;
  const int l = t & 63;
  const int wid = t >> 6;
  const int wr = wid >> 2;          // 0..1
  const int wc = wid & 3;           // 0..3
  const int lg = l >> 4;            // 0..3
  const int ll = l & 15;
  const int e0 = blockIdx.x * 128;

  // ---- B stage issue: global(pre-swizzled addr) -> linear LDS (rule #21) ----
  auto issue = [&](int s) {
    int sc = (s < ST) ? s : (ST - 1);             // clamp tail (dummy, unread)
    int q, nc, ks;
    if (sc < S8) {
      q = sc >> (NC == 8 ? 5 : 4);
      int r = sc & (NC * 4 - 1);
      nc = r >> 2; ks = r & 3;
    } else { q = 8; nc = sc - S8; ks = 0; }
    const int qb = (q < 8) ? q * 128 : 1024;
    unsigned short* bbuf = sB[s % 3];
    #pragma unroll
    for (int j = 0; j < 2; ++j) {
      int sl = t + j * 512;                       // 0..1023 slice of 16B
      int n = sl >> 2, slot = sl & 3;
      const unsigned short* src =
          WT + (size_t)(nc * 256 + n) * KW + qb + ks * 32 + 8 * (slot ^ ((n >> 1) & 3));
      unsigned short* dst = bbuf + (size_t)(wid * 64 + j * 512) * 8;  // wave-uniform base
      gload_lds16(src, dst);
    }
  };

  // ---- build hidden chunk q (k in [q*128, q*128+128)) into sHid ----
  auto build = [&](int q) {
    int m = t >> 2, kq = (t & 3) * 32;
    const unsigned short* p0 = tab0 + (size_t)sb0[m] * 1024 + q * 128 + kq;
    const unsigned short* p1 = tab1 + (size_t)sb1[m] * 1024 + q * 128 + kq;
    #pragma unroll
    for (int j = 0; j < 4; ++j) {
      u16x8 a = *(const u16x8*)(p0 + j * 8);
      u16x8 b = *(const u16x8*)(p1 + j * 8);
      u16x8 h;
      #pragma unroll
      for (int u = 0; u < 8; ++u)
        h[u] = f2bf(fmaxf(bf2f(a[u]) + bf2f(b[u]), 0.f));
      int kb = (t & 3) * 4 + j;
      *(u16x8*)&sHid[m * 128 + 8 * (kb ^ (m & 15))] = h;
    }
  };

  // ---- prologue ----
  issue(0); issue(1);
  if (t < 128) {
    int e = e0 + t;
    if (e < E_N) {
      sSrc[t] = ei[e]; sDst[t] = ei[E_N + e];
      sb0[t] = (unsigned char)(eap[2 * e] & 255);
      sb1[t] = (unsigned char)(eap[2 * e + 1] & 255);
    } else { sSrc[t] = 0; sDst[t] = -1; sb0[t] = 0; sb1[t] = 0; }
  }
  __syncthreads();
  for (int j = t; j < 128 * 32; j += 512) {
    int m = j >> 5, i = j & 31;
    sXf[j] = (e0 + m < E_N) ? xsrc[(size_t)sSrc[m] * 32 + i] : 0.f;
  }
  build(0);
  __syncthreads();

  float msgr[4][4] = {};
  const f32x4 zf = {0.f, 0.f, 0.f, 0.f};
  s8v avm = {};                       // mini-chunk A: hid[·][1024]=1
  if (lg == 0) avm[0] = (short)0x3F80;
  int sidx = 0;

  for (int q = 0; q < 9; ++q) {
    s8v avq[4][4];
    if (q < 8) {
      #pragma unroll
      for (int mf = 0; mf < 4; ++mf) {
        int row = wr * 64 + mf * 16 + ll;
        #pragma unroll
        for (int ks = 0; ks < 4; ++ks) {
          int kb = ks * 4 + lg;
          avq[mf][ks] = *(const s8v*)&sHid[row * 128 + 8 * (kb ^ (row & 15))];
        }
      }
    }
    for (int nc = 0; nc < NC; ++nc) {
      const int i0 = (FOUT == 64) ? nc * 4 : nc * 8 + (wc >> 1) * 4;
      const int nb = (FOUT == 64) ? wc * 16 + ll : (wc >> 1) * 128 + (wc & 1) * 16 + ll;
      f32x4 acc[4][4];

      if (q < 8) {
        #pragma unroll
        for (int ks = 0; ks < 4; ++ks) {
          asm volatile("s_waitcnt vmcnt(2)" ::: "memory");   // stage sidx landed (T4)
          __builtin_amdgcn_s_barrier();                      // all waves: loads done, prev reads done
          asm volatile("" ::: "memory");
          issue(sidx + 2);
          const unsigned short* bbuf = sB[sidx % 3];
          s8v bv[4];
          #pragma unroll
          for (int nf = 0; nf < 4; ++nf) {
            int n = (FOUT == 64) ? nf * 64 + nb : nb + nf * 32;
            bv[nf] = *(const s8v*)&bbuf[n * 32 + 8 * (lg ^ ((n >> 1) & 3))];
          }
          __builtin_amdgcn_s_setprio(1);
          #pragma unroll
          for (int mf = 0; mf < 4; ++mf)
            #pragma unroll
            for (int nf = 0; nf < 4; ++nf)
              acc[mf][nf] = __builtin_amdgcn_mfma_f32_16x16x32_bf16(
                  avq[mf][ks], bv[nf], (ks == 0) ? zf : acc[mf][nf], 0, 0, 0);
          __builtin_amdgcn_s_setprio(0);
          ++sidx;
        }
      } else {
        asm volatile("s_waitcnt vmcnt(2)" ::: "memory");
        __builtin_amdgcn_s_barrier();
        asm volatile("" ::: "memory");
        issue(sidx + 2);
        const unsigned short* bbuf = sB[sidx % 3];
        s8v bv[4];
        #pragma unroll
        for (int nf = 0; nf < 4; ++nf) {
          int n = (FOUT == 64) ? nf * 64 + nb : nb + nf * 32;
          bv[nf] = *(const s8v*)&bbuf[n * 32 + 8 * (lg ^ ((n >> 1) & 3))];
        }
        __builtin_amdgcn_s_setprio(1);
        #pragma unroll
        for (int mf = 0; mf < 4; ++mf)
          #pragma unroll
          for (int nf = 0; nf < 4; ++nf)
            acc[mf][nf] = __builtin_amdgcn_mfma_f32_16x16x32_bf16(avm, bv[nf], zf, 0, 0, 0);
        __builtin_amdgcn_s_setprio(0);
        ++sidx;
      }

      // contract partial theta into per-lane msg (linearity over K-chunks)
      #pragma unroll
      for (int mf = 0; mf < 4; ++mf) {
        #pragma unroll
        for (int r = 0; r < 4; ++r) {
          int row = wr * 64 + mf * 16 + lg * 4 + r;
          f32x4 xv = *(const f32x4*)&sXf[row * 32 + i0];    // ll-broadcast read
          #pragma unroll
          for (int nf = 0; nf < 4; ++nf)
            msgr[mf][r] += acc[mf][nf][r] * xv[nf];
        }
      }
    }
    if (q < 7) { __syncthreads(); build(q + 1); __syncthreads(); }
  }

  // ---- epilogue: each lane owns (row, o) uniquely per wave-pair; scatter ----
  const int o = ((FOUT == 64) ? wc * 16 : (wc & 1) * 16) + ll;
  #pragma unroll
  for (int mf = 0; mf < 4; ++mf)
    #pragma unroll
    for (int r = 0; r < 4; ++r) {
      int row = wr * 64 + mf * 16 + lg * 4 + r;
      int d = sDst[row];
      if (d >= 0) atomicAdd(&agg[(size_t)d * FOUT + o], msgr[mf][r]);
    }
}

// ---------------- node update / pool / MLP ----------------

__global__ void k_node1(const float* __restrict__ x, const float* __restrict__ agg,
                        const int* __restrict__ cnt, const float* __restrict__ root,
                        const float* __restrict__ bias, float* __restrict__ h) {
  int tid = blockIdx.x * 256 + threadIdx.x;
  if (tid >= NV_N * 32) return;
  int n = tid >> 5, j = tid & 31;
  const float* xr = x + n * 32;
  float s = 0.f;
  #pragma unroll
  for (int i = 0; i < 32; ++i) s = fmaf(xr[i], root[i * 32 + j], s);
  int c = cnt[n]; if (c < 1) c = 1;
  h[tid] = fmaxf(agg[tid] / (float)c + s + bias[j], 0.f);
}

__global__ void k_node2(const float* __restrict__ hin, const float* __restrict__ agg,
                        const int* __restrict__ cnt, const float* __restrict__ root,
                        const float* __restrict__ bias, float* __restrict__ h2) {
  int tid = blockIdx.x * 256 + threadIdx.x;
  if (tid >= NV_N * 64) return;
  int n = tid >> 6, j = tid & 63;
  const float* xr = hin + n * 32;
  float s = 0.f;
  #pragma unroll
  for (int i = 0; i < 32; ++i) s = fmaf(xr[i], root[i * 64 + j], s);
  int c = cnt[n]; if (c < 1) c = 1;
  h2[tid] = fmaxf(agg[tid] / (float)c + s + bias[j], 0.f);
}

__device__ __forceinline__ int lowerb(const int* __restrict__ a, int n, int key) {
  int lo = 0, hi = n;
  while (lo < hi) { int mid = (lo + hi) >> 1; if (a[mid] < key) lo = mid + 1; else hi = mid; }
  return lo;
}

__global__ void k_pool(const float* __restrict__ h2, const int* __restrict__ batch,
                       float* __restrict__ g) {
  int gid = (blockIdx.x * 256 + threadIdx.x) >> 6;
  int l = threadIdx.x & 63;
  if (gid >= NG_N) return;
  int lo = lowerb(batch, NV_N, gid);
  int hi = lowerb(batch, NV_N, gid + 1);
  float s = 0.f;
  for (int n = lo; n < hi; ++n) s += h2[n * 64 + l];
  int c = hi - lo; if (c < 1) c = 1;
  g[gid * 64 + l] = s / (float)c;
}

template<int K, bool RELU>
__global__ void k_fc(const float* __restrict__ A, const float* __restrict__ W,
                     const float* __restrict__ bias, float* __restrict__ out, int N) {
  __shared__ float sA[8][K];
  int r0 = blockIdx.x * 8;
  int n = blockIdx.y * 256 + threadIdx.x;
  for (int j = threadIdx.x; j < 8 * K; j += 256) {
    int rr = j / K, kk = j - rr * K;
    int r = r0 + rr;
    sA[rr][kk] = (r < NG_N) ? A[r * K + kk] : 0.f;
  }
  __syncthreads();
  float acc[8] = {0.f, 0.f, 0.f, 0.f, 0.f, 0.f, 0.f, 0.f};
  for (int k = 0; k < K; ++k) {
    float b = W[k * N + n];
    #pragma unroll
    for (int rr = 0; rr < 8; ++rr) acc[rr] = fmaf(sA[rr][k], b, acc[rr]);
  }
  float bs = bias[n];
  #pragma unroll
  for (int rr = 0; rr < 8; ++rr) {
    int r = r0 + rr;
    if (r < NG_N) {
      float v = acc[rr] + bs;
      if (RELU) v = fmaxf(v, 0.f);
      out[r * N + n] = v;
    }
  }
}

__global__ void k_fc4(const float* __restrict__ A, const float* __restrict__ W,
                      const float* __restrict__ bias, float* __restrict__ out) {
  int tid = blockIdx.x * 256 + threadIdx.x;
  int r = tid >> 2, s = tid & 3;
  if (r >= NG_N || s >= 3) return;
  float acc = bias[s];
  for (int k = 0; k < 256; ++k) acc = fmaf(A[r * 256 + k], W[k * 3 + s], acc);
  out[r * 3 + s] = acc;
}

// ---------------- launch ----------------

extern "C" void kernel_launch(void* const* d_in, const int* in_sizes, int n_in,
                              void* d_out, int out_size, void* d_ws, size_t ws_size,
                              hipStream_t stream) {
  const float* x     = (const float*)d_in[0];
  const int*   ei    = (const int*)d_in[1];
  const int*   eap   = (const int*)d_in[2];
  const int*   batch = (const int*)d_in[3];
  const float* W1a   = (const float*)d_in[4];
  const float* b1a   = (const float*)d_in[5];
  const float* W1b   = (const float*)d_in[6];
  const float* b1b   = (const float*)d_in[7];
  const float* W2a   = (const float*)d_in[8];
  const float* b2a   = (const float*)d_in[9];
  const float* W2b   = (const float*)d_in[10];
  const float* b2b   = (const float*)d_in[11];
  const float* root1 = (const float*)d_in[12];
  const float* bias1 = (const float*)d_in[13];
  const float* root2 = (const float*)d_in[14];
  const float* bias2 = (const float*)d_in[15];
  const float* fcW1  = (const float*)d_in[16];
  const float* fcb1  = (const float*)d_in[17];
  const float* fcW2  = (const float*)d_in[18];
  const float* fcb2  = (const float*)d_in[19];
  const float* fcW3  = (const float*)d_in[20];
  const float* fcb3  = (const float*)d_in[21];
  const float* fcW4  = (const float*)d_in[22];
  const float* fcb4  = (const float*)d_in[23];
  float* out = (float*)d_out;

  char* w = (char*)d_ws;
  size_t off = 0;
  auto take = [&](size_t bytes) -> void* {
    void* p = w + off;
    off = (off + bytes + 255) & ~(size_t)255;
    return p;
  };
  unsigned short* tabs = (unsigned short*)take(4 * 256 * 1024 * 2);
  unsigned short* w1t  = (unsigned short*)take((size_t)1024 * KW * 2);
  unsigned short* w2t  = (unsigned short*)take((size_t)2048 * KW * 2);
  float* agg1 = (float*)take((size_t)NV_N * 32 * 4);
  float* agg2 = (float*)take((size_t)NV_N * 64 * 4);
  int*   cnt  = (int*)take((size_t)NV_N * 4);
  float* h    = (float*)take((size_t)NV_N * 32 * 4);
  float* h2   = (float*)take((size_t)NV_N * 64 * 4);
  float* g    = (float*)take((size_t)NG_N * 64 * 4);
  float* l1   = (float*)take((size_t)NG_N * 512 * 4);
  float* l2   = (float*)take((size_t)NG_N * 512 * 4);
  float* l3   = (float*)take((size_t)NG_N * 256 * 4);

  hipMemsetAsync(agg1, 0, (size_t)NV_N * 32 * 4, stream);
  hipMemsetAsync(agg2, 0, (size_t)NV_N * 64 * 4, stream);
  hipMemsetAsync(cnt, 0, (size_t)NV_N * 4, stream);

  k_tables<<<4096, 256, 0, stream>>>(W1a, b1a, W2a, b2a, tabs);
  k_transpose<<<(1024 / 32) * (1024 / 32), 256, 0, stream>>>(W1b, w1t, 1024, 1024);
  k_transpose<<<(1024 / 32) * (2048 / 32), 256, 0, stream>>>(W2b, w2t, 1024, 2048);
  k_biasrow<<<(1024 * 64 + 255) / 256, 256, 0, stream>>>(b1b, w1t, 1024);
  k_biasrow<<<(2048 * 64 + 255) / 256, 256, 0, stream>>>(b2b, w2t, 2048);
  k_count<<<(E_N + 255) / 256, 256, 0, stream>>>(ei, cnt);

  const int nblk = (E_N + 127) / 128;
  k_edge<1024, 32><<<nblk, 512, 0, stream>>>(x, ei, eap, tabs, tabs + 262144,
                                             w1t, agg1);
  k_node1<<<(NV_N * 32) / 256, 256, 0, stream>>>(x, agg1, cnt, root1, bias1, h);

  k_edge<2048, 64><<<nblk, 512, 0, stream>>>(h, ei, eap, tabs + 2 * 262144, tabs + 3 * 262144,
                                             w2t, agg2);
  k_node2<<<(NV_N * 64) / 256, 256, 0, stream>>>(h, agg2, cnt, root2, bias2, h2);

  k_pool<<<(NG_N * 64) / 256, 256, 0, stream>>>(h2, batch, g);

  k_fc<64, true><<<dim3((NG_N + 7) / 8, 2), 256, 0, stream>>>(g, fcW1, fcb1, l1, 512);
  k_fc<512, true><<<dim3((NG_N + 7) / 8, 2), 256, 0, stream>>>(l1, fcW2, fcb2, l2, 512);
  k_fc<512, true><<<dim3((NG_N + 7) / 8, 1), 256, 0, stream>>>(l2, fcW3, fcb3, l3, 256);
  k_fc4<<<(NG_N * 4 + 255) / 256, 256, 0, stream>>>(l3, fcW4, fcb4, out);
}